// Round 5
// baseline (256.883 us; speedup 1.0000x reference)
//
#include <hip/hip_runtime.h>
#include <stdint.h>

#define B_     64
#define N_     197
#define DIM_   768
#define HEADS_ 12
#define HD_    64
#define M_     (B_*N_)      // 12608
#define K3_    (3*DIM_)     // 2304
#define NP_    208          // padded N (13*16)
#define KSTR_  72           // attn K_lds row stride (f16)
#define VSTR_  232          // attn VT / P row stride (f16)
#define SCALE_ 0.125f
#define GK_    768          // GEMM K (both gemms)
#define NKT2_  12           // GK_/64

typedef _Float16 f16x8 __attribute__((ext_vector_type(8)));
typedef _Float16 f16x4 __attribute__((ext_vector_type(4)));
typedef _Float16 f16x2 __attribute__((ext_vector_type(2)));
typedef float    f32x4 __attribute__((ext_vector_type(4)));

__device__ __forceinline__ void gload_lds16(const void* g, void* l) {
    __builtin_amdgcn_global_load_lds(
        (const __attribute__((address_space(1))) uint32_t*)g,
        (__attribute__((address_space(3))) uint32_t*)l, 16, 0, 0);
}

#define VMW0() asm volatile("s_waitcnt vmcnt(0)" ::: "memory")

// ---------------- f32 -> f16 convert ----------------
__global__ __launch_bounds__(256) void cvt_f32_f16(const float* __restrict__ s,
                                                   _Float16* __restrict__ d, int n4) {
    int i = blockIdx.x * 256 + threadIdx.x;
    if (i < n4) {
        const float4 v = *(const float4*)(s + (size_t)i * 4);
        f16x4 o;
        o[0] = (_Float16)v.x; o[1] = (_Float16)v.y;
        o[2] = (_Float16)v.z; o[3] = (_Float16)v.w;
        *(f16x4*)(d + (size_t)i * 4) = o;
    }
}

// ---------------- transposed rel-pos bias: biasT[h][k][q], padded 208x208 ----------------
__global__ __launch_bounds__(256) void biasT_pre(const int* __restrict__ rel_index,
                                                 const float* __restrict__ rel_table,
                                                 float* __restrict__ biasT) {
    int t = blockIdx.x * 256 + threadIdx.x;
    if (t < HEADS_ * NP_ * NP_) {
        int h = t / (NP_ * NP_), rem = t - h * (NP_ * NP_);
        int k = rem / NP_, q = rem - k * NP_;
        float v;
        if (k >= N_)      v = -1e30f;   // padded key -> exp()->0
        else if (q >= N_) v = 0.f;      // padded query -> finite, never stored
        else              v = rel_table[rel_index[q * N_ + k] * HEADS_ + h];
        biasT[t] = v;
    }
}

// ---------------- double-buffered 128x128 MFMA GEMM, BK=64 ----------------
// C[M x Nout] = A[M x 768] * Bw[Nout x 768]^T (+ bias per mode)
// LDS slot = [128 rows][32 k] f16 (8KB), 4 waves stage rows w*32..+31.
// Swizzle (zero-conflict, verified r3): write linear granules (gload_lds),
// per-lane source permuted by lx = lane^(lane>>3); read granule (4fr+g)^(fr>>1).
__global__ __launch_bounds__(256, 2) void gemm_db(
    const _Float16* __restrict__ A, const _Float16* __restrict__ Bw,
    int M, int Nout, int mode,
    const float* __restrict__ qb, const float* __restrict__ vb,
    const float* __restrict__ pb, const int* __restrict__ b_idx,
    _Float16* __restrict__ out_h, float* __restrict__ out_f)
{
    __shared__ __align__(16) _Float16 As[2][2][4096];   // [buf][khalf][128*32]
    __shared__ __align__(16) _Float16 Bs[2][2][4096];

    const int tid  = threadIdx.x;
    const int lane = tid & 63, w = tid >> 6;
    const int wm = w >> 1, wn = w & 1;                  // 2x2 waves, 64x64 each
    const int fr = lane & 15, g = lane >> 4;
    const int gl8 = ((4 * fr + g) ^ (fr >> 1)) * 8;     // swizzled read offset (elems)
    const int lx = lane ^ (lane >> 3);                  // staging source permutation
    const int sr = lx >> 2, sc8 = (lx & 3) * 8;
    const int m0 = blockIdx.x * 128, n0 = blockIdx.y * 128;  // x = M-tile (B-panel L2 reuse)

    f32x4 acc[4][4];
    #pragma unroll
    for (int i = 0; i < 4; ++i)
        #pragma unroll
        for (int j = 0; j < 4; ++j) acc[i][j] = (f32x4)0.f;

    // stage one [128][32] half-slot: 2 gload_lds per thread
    auto stA = [&](int buf, int kh, int kt) {
        #pragma unroll
        for (int iss = 0; iss < 2; ++iss) {
            int grow = m0 + w * 32 + iss * 16 + sr;
            if (grow >= M) grow = M - 1;
            gload_lds16(A + (size_t)grow * GK_ + kt * 64 + kh * 32 + sc8,
                        &As[buf][kh][w * 1024 + iss * 512]);
        }
    };
    auto stB = [&](int buf, int kh, int kt) {
        #pragma unroll
        for (int iss = 0; iss < 2; ++iss) {
            int grow = n0 + w * 32 + iss * 16 + sr;     // Nout % 128 == 0, no clamp
            gload_lds16(Bw + (size_t)grow * GK_ + kt * 64 + kh * 32 + sc8,
                        &Bs[buf][kh][w * 1024 + iss * 512]);
        }
    };

    // prologue: fill buf0 with kt=0
    stA(0, 0, 0); stA(0, 1, 0); stB(0, 0, 0); stB(0, 1, 0);
    VMW0();
    __builtin_amdgcn_s_barrier();

    for (int t = 0; t < NKT2_; ++t) {
        const int cur = t & 1;
        if (t + 1 < NKT2_) {                            // prefetch next K-tile
            stA(cur ^ 1, 0, t + 1); stA(cur ^ 1, 1, t + 1);
            stB(cur ^ 1, 0, t + 1); stB(cur ^ 1, 1, t + 1);
        }
        #pragma unroll
        for (int kh = 0; kh < 2; ++kh) {
            f16x8 av[4], bv[4];
            #pragma unroll
            for (int i = 0; i < 4; ++i)
                av[i] = *(const f16x8*)&As[cur][kh][wm * 2048 + i * 512 + gl8];
            #pragma unroll
            for (int j = 0; j < 4; ++j)
                bv[j] = *(const f16x8*)&Bs[cur][kh][wn * 2048 + j * 512 + gl8];
            #pragma unroll
            for (int i = 0; i < 4; ++i)
                #pragma unroll
                for (int j = 0; j < 4; ++j)
                    acc[i][j] = __builtin_amdgcn_mfma_f32_16x16x32_f16(av[i], bv[j], acc[i][j], 0, 0, 0);
        }
        if (t + 1 < NKT2_) {
            VMW0();                                     // issued one full compute phase ago
            __builtin_amdgcn_s_barrier();
        }
    }

    // epilogue: C/D layout col=fr, row=g*4+rr
    #pragma unroll
    for (int mi = 0; mi < 4; ++mi) {
        #pragma unroll
        for (int rr = 0; rr < 4; ++rr) {
            const int row = m0 + wm * 64 + mi * 16 + g * 4 + rr;
            if (row < M) {
                const int bi = b_idx[row / N_];
                #pragma unroll
                for (int ni = 0; ni < 4; ++ni) {
                    const int col = n0 + wn * 64 + ni * 16 + fr;
                    float v = acc[mi][ni][rr];
                    if (mode == 0) {
                        float bias = 0.f;
                        if (col < DIM_) bias = qb[bi * DIM_ + col];
                        else if (col >= 2 * DIM_) bias = vb[bi * DIM_ + (col - 2 * DIM_)];
                        out_h[(size_t)row * Nout + col] = (_Float16)(v + bias);
                    } else {
                        out_f[(size_t)row * Nout + col] = v + pb[bi * DIM_ + col];
                    }
                }
            }
        }
    }
}

// ---------------- MFMA attention: one block per (b, h, 64-row q-tile) ----------------
__global__ __launch_bounds__(256) void attn_mfma(
    const _Float16* __restrict__ qkv, const float* __restrict__ biasT,
    _Float16* __restrict__ ctx)
{
    __shared__ __align__(16) _Float16 KP[NP_ * KSTR_];   // K tile, reused as P tile
    __shared__ __align__(16) _Float16 VT[HD_ * VSTR_];   // V^T tile

    const int b = blockIdx.z, h = blockIdx.y, rt = blockIdx.x;
    const int r0 = rt * 64;
    const int tid = threadIdx.x, lane = tid & 63, w = tid >> 6;
    const int fr = lane & 15, g = lane >> 4;

    const size_t baseQ = (size_t)b * N_ * K3_ + h * HD_;
    const size_t baseK = baseQ + DIM_;
    const size_t baseV = baseQ + 2 * DIM_;

    for (int idx = tid; idx < NP_ * 8; idx += 256) {
        int row = idx % NP_, dc = idx / NP_;
        int gk = min(row, N_ - 1);
        f16x8 v = *(const f16x8*)(qkv + baseK + (size_t)gk * K3_ + dc * 8);
        *(f16x8*)(KP + row * KSTR_ + dc * 8) = v;
    }
    for (int idx = tid; idx < 112 * 8; idx += 256) {
        int jp = idx % 112, dc = idx / 112;
        int j0 = 2 * jp, j1 = 2 * jp + 1;
        f16x8 zz = {};
        f16x8 v0 = (j0 < N_) ? *(const f16x8*)(qkv + baseV + (size_t)j0 * K3_ + dc * 8) : zz;
        f16x8 v1 = (j1 < N_) ? *(const f16x8*)(qkv + baseV + (size_t)j1 * K3_ + dc * 8) : zz;
        #pragma unroll
        for (int e = 0; e < 8; ++e) {
            f16x2 p; p[0] = v0[e]; p[1] = v1[e];
            *(f16x2*)(VT + (dc * 8 + e) * VSTR_ + 2 * jp) = p;
        }
    }
    const int qrow = min(r0 + w * 16 + fr, N_ - 1);
    f16x8 qf[2];
    qf[0] = *(const f16x8*)(qkv + baseQ + (size_t)qrow * K3_ + g * 8);
    qf[1] = *(const f16x8*)(qkv + baseQ + (size_t)qrow * K3_ + 32 + g * 8);

    __syncthreads();

    f32x4 acc[13];
    #pragma unroll
    for (int jf = 0; jf < 13; ++jf) acc[jf] = (f32x4)0.f;
    #pragma unroll
    for (int jf = 0; jf < 13; ++jf) {
        #pragma unroll
        for (int kk = 0; kk < 2; ++kk) {
            f16x8 a = *(const f16x8*)&KP[(jf * 16 + fr) * KSTR_ + kk * 32 + g * 8];
            acc[jf] = __builtin_amdgcn_mfma_f32_16x16x32_f16(a, qf[kk], acc[jf], 0, 0, 0);
        }
    }

    const int qb_ = min(r0 + w * 16 + fr, NP_ - 1);
    const float* bp = biasT + (size_t)h * NP_ * NP_ + qb_;
    float mx = -3e38f;
    #pragma unroll
    for (int jf = 0; jf < 13; ++jf) {
        #pragma unroll
        for (int r = 0; r < 4; ++r) {
            int k = jf * 16 + g * 4 + r;
            float s = acc[jf][r] * SCALE_ + bp[(size_t)k * NP_];
            acc[jf][r] = s;
            mx = fmaxf(mx, s);
        }
    }
    mx = fmaxf(mx, __shfl_xor(mx, 16));
    mx = fmaxf(mx, __shfl_xor(mx, 32));
    float sum = 0.f;
    #pragma unroll
    for (int jf = 0; jf < 13; ++jf) {
        #pragma unroll
        for (int r = 0; r < 4; ++r) {
            float e = __expf(acc[jf][r] - mx);
            acc[jf][r] = e;
            sum += e;
        }
    }
    sum += __shfl_xor(sum, 16);
    sum += __shfl_xor(sum, 32);
    const float inv = 1.f / sum;

    __syncthreads();

    #pragma unroll
    for (int jf = 0; jf < 13; ++jf) {
        f16x4 p;
        #pragma unroll
        for (int r = 0; r < 4; ++r) p[r] = (_Float16)(acc[jf][r] * inv);
        *(f16x4*)(KP + (size_t)(w * 16 + fr) * VSTR_ + jf * 16 + g * 4) = p;
    }
    {
        f16x4 z = {};
        *(f16x4*)(KP + (size_t)(w * 16 + fr) * VSTR_ + NP_ + g * 4) = z;
    }
    __syncthreads();

    f32x4 oacc[4];
    #pragma unroll
    for (int dj = 0; dj < 4; ++dj) oacc[dj] = (f32x4)0.f;
    #pragma unroll
    for (int ks = 0; ks < 7; ++ks) {
        f16x8 a = *(const f16x8*)&KP[(size_t)(w * 16 + fr) * VSTR_ + ks * 32 + g * 8];
        #pragma unroll
        for (int dj = 0; dj < 4; ++dj) {
            f16x8 bf = *(const f16x8*)&VT[(dj * 16 + fr) * VSTR_ + ks * 32 + g * 8];
            oacc[dj] = __builtin_amdgcn_mfma_f32_16x16x32_f16(a, bf, oacc[dj], 0, 0, 0);
        }
    }
    #pragma unroll
    for (int dj = 0; dj < 4; ++dj) {
        #pragma unroll
        for (int r = 0; r < 4; ++r) {
            const int q = r0 + w * 16 + g * 4 + r;
            if (q < N_)
                ctx[((size_t)b * N_ + q) * DIM_ + h * HD_ + dj * 16 + fr] =
                    (_Float16)oacc[dj][r];
        }
    }
}

// ---------------- launcher ----------------
extern "C" void kernel_launch(void* const* d_in, const int* in_sizes, int n_in,
                              void* d_out, int out_size, void* d_ws, size_t ws_size,
                              hipStream_t stream) {
    const float* x     = (const float*)d_in[0];
    const float* wqkv  = (const float*)d_in[1];
    const float* qb    = (const float*)d_in[2];
    const float* vb    = (const float*)d_in[3];
    const float* rt    = (const float*)d_in[4];
    const float* wproj = (const float*)d_in[5];
    const float* pbias = (const float*)d_in[6];
    const int* b_idx   = (const int*)d_in[7];
    const int* rel_idx = (const int*)d_in[8];
    float* out = (float*)d_out;

    char* ws = (char*)d_ws;
    size_t off = 0;
    auto alloc = [&](size_t bytes) -> void* {
        void* p = ws + off; off += (bytes + 255) & ~(size_t)255; return p;
    };
    _Float16* xb    = (_Float16*)alloc((size_t)M_ * DIM_ * 2);
    _Float16* wqh   = (_Float16*)alloc((size_t)K3_ * DIM_ * 2);
    _Float16* wph   = (_Float16*)alloc((size_t)DIM_ * DIM_ * 2);
    _Float16* qkvh  = (_Float16*)alloc((size_t)M_ * K3_ * 2);
    _Float16* ctx   = (_Float16*)alloc((size_t)M_ * DIM_ * 2);
    float*    biasT = (float*)alloc((size_t)HEADS_ * NP_ * NP_ * 4);

    cvt_f32_f16<<<dim3((M_ * DIM_ / 4 + 255) / 256), 256, 0, stream>>>(x, xb, M_ * DIM_ / 4);
    cvt_f32_f16<<<dim3((K3_ * DIM_ / 4 + 255) / 256), 256, 0, stream>>>(wqkv, wqh, K3_ * DIM_ / 4);
    cvt_f32_f16<<<dim3((DIM_ * DIM_ / 4 + 255) / 256), 256, 0, stream>>>(wproj, wph, DIM_ * DIM_ / 4);
    biasT_pre<<<dim3((HEADS_ * NP_ * NP_ + 255) / 256), 256, 0, stream>>>(rel_idx, rt, biasT);

    gemm_db<<<dim3((M_ + 127) / 128, K3_ / 128), 256, 0, stream>>>(
        xb, wqh, M_, K3_, 0, qb, vb, nullptr, b_idx, qkvh, nullptr);

    attn_mfma<<<dim3(4, HEADS_, B_), 256, 0, stream>>>(qkvh, biasT, ctx);

    gemm_db<<<dim3((M_ + 127) / 128, DIM_ / 128), 256, 0, stream>>>(
        ctx, wph, M_, DIM_, 1, nullptr, nullptr, pbias, b_idx, nullptr, out);
}

// Round 6
// 197.514 us; speedup vs baseline: 1.3006x; 1.3006x over previous
//
#include <hip/hip_runtime.h>
#include <stdint.h>

#define B_     64
#define N_     197
#define DIM_   768
#define HEADS_ 12
#define HD_    64
#define M_     (B_*N_)      // 12608
#define K3_    (3*DIM_)     // 2304
#define NP_    208          // padded N (13*16)
#define KSTR_  72           // attn K_lds row stride (f16)
#define VSTR_  232          // attn VT / P row stride (f16)
#define SCALE_ 0.125f
#define GK_    768          // GEMM K (both gemms)
#define NKT_   24           // GK_/32

typedef _Float16 f16x8 __attribute__((ext_vector_type(8)));
typedef _Float16 f16x4 __attribute__((ext_vector_type(4)));
typedef _Float16 f16x2 __attribute__((ext_vector_type(2)));
typedef float    f32x4 __attribute__((ext_vector_type(4)));

__device__ __forceinline__ void gload_lds16(const void* g, void* l) {
    __builtin_amdgcn_global_load_lds(
        (const __attribute__((address_space(1))) uint32_t*)g,
        (__attribute__((address_space(3))) uint32_t*)l, 16, 0, 0);
}

#define VMW0() asm volatile("s_waitcnt vmcnt(0)" ::: "memory")

// ---------------- f32 -> f16 convert ----------------
__global__ __launch_bounds__(256) void cvt_f32_f16(const float* __restrict__ s,
                                                   _Float16* __restrict__ d, int n4) {
    int i = blockIdx.x * 256 + threadIdx.x;
    if (i < n4) {
        const float4 v = *(const float4*)(s + (size_t)i * 4);
        f16x4 o;
        o[0] = (_Float16)v.x; o[1] = (_Float16)v.y;
        o[2] = (_Float16)v.z; o[3] = (_Float16)v.w;
        *(f16x4*)(d + (size_t)i * 4) = o;
    }
}

// ---------------- transposed rel-pos bias: biasT[h][k][q], padded 208x208 ----------------
__global__ __launch_bounds__(256) void biasT_pre(const int* __restrict__ rel_index,
                                                 const float* __restrict__ rel_table,
                                                 float* __restrict__ biasT) {
    int t = blockIdx.x * 256 + threadIdx.x;
    if (t < HEADS_ * NP_ * NP_) {
        int h = t / (NP_ * NP_), rem = t - h * (NP_ * NP_);
        int k = rem / NP_, q = rem - k * NP_;
        float v;
        if (k >= N_)      v = -1e30f;   // padded key -> exp()->0
        else if (q >= N_) v = 0.f;      // padded query -> finite, never stored
        else              v = rel_table[rel_index[q * N_ + k] * HEADS_ + h];
        biasT[t] = v;
    }
}

// ---------------- 256x128 double-buffered MFMA GEMM, BK=32, XCD-chunked grid ----
// C[M x Nout] = A[M x 768] * Bw[Nout x 768]^T (+ bias per MODE)
// 512 thr = 8 waves (4 M x 2 N), each wave 64x64 output.
// LDS per buf: A 16KB (16 chunks of [16 rows][32 k]) + B 8KB (8 chunks). x2 bufs = 48KB.
// Granule swizzle (zero-conflict, verified r3/r4): linear gload_lds dest,
// source lane permuted lx = lane^(lane>>3); read granule ((4fr+g)^(fr>>1)).
template <int MODE>
__global__ __launch_bounds__(512, 2) void gemm_db(
    const _Float16* __restrict__ A, const _Float16* __restrict__ Bw,
    int M, int Nout,
    const float* __restrict__ qb, const float* __restrict__ vb,
    const float* __restrict__ pb, const int* __restrict__ b_idx,
    _Float16* __restrict__ out_h, float* __restrict__ out_f)
{
    __shared__ __align__(16) _Float16 As[2][16 * 512];
    __shared__ __align__(16) _Float16 Bs[2][8 * 512];

    const int tid  = threadIdx.x;
    const int lane = tid & 63, w = tid >> 6;
    const int wm = w >> 1, wn = w & 1;              // 4 M-waves x 2 N-waves
    const int fr = lane & 15, g = lane >> 4;
    const int gl8 = ((4 * fr + g) ^ (fr >> 1)) * 8; // swizzled read offset in chunk
    const int lx = lane ^ (lane >> 3);              // staging source permutation
    const int sr = lx >> 2, sc8 = (lx & 3) * 8;

    // ---- bijective XCD-chunk swizzle (m204) ----
    const int gx = Nout / 128;                      // N-tiles (inner)
    const int gy = (M + 255) / 256;                 // M-tiles
    const int nwg = gx * gy;
    const int wgid = blockIdx.x + blockIdx.y * gx;
    const int q8 = nwg >> 3, r8 = nwg & 7;
    const int xcd = wgid & 7, lid = wgid >> 3;
    const int nid = (xcd < r8) ? xcd * (q8 + 1) + lid
                               : r8 * (q8 + 1) + (xcd - r8) * q8 + lid;
    const int m0 = (nid / gx) * 256, n0 = (nid % gx) * 128;

    f32x4 acc[4][4];
    #pragma unroll
    for (int i = 0; i < 4; ++i)
        #pragma unroll
        for (int j = 0; j < 4; ++j) acc[i][j] = (f32x4)0.f;

    // stage K-tile kt into buf: per thread 2 A-gloads (chunks 2w, 2w+1) + 1 B-gload (chunk w)
    auto stage = [&](int buf, int kt) {
        #pragma unroll
        for (int iss = 0; iss < 2; ++iss) {
            int grow = m0 + w * 32 + iss * 16 + sr;
            if (grow >= M) grow = M - 1;
            gload_lds16(A + (size_t)grow * GK_ + kt * 32 + sc8,
                        &As[buf][(2 * w + iss) * 512]);
        }
        int brow = n0 + w * 16 + sr;                // Nout % 128 == 0
        gload_lds16(Bw + (size_t)brow * GK_ + kt * 32 + sc8,
                    &Bs[buf][w * 512]);
    };

    stage(0, 0);
    VMW0();
    __builtin_amdgcn_s_barrier();

    for (int t = 0; t < NKT_; ++t) {
        const int cur = t & 1;
        if (t + 1 < NKT_) stage(cur ^ 1, t + 1);
        f16x8 av[4], bv[4];
        #pragma unroll
        for (int i = 0; i < 4; ++i)
            av[i] = *(const f16x8*)&As[cur][(wm * 4 + i) * 512 + gl8];
        #pragma unroll
        for (int j = 0; j < 4; ++j)
            bv[j] = *(const f16x8*)&Bs[cur][(wn * 4 + j) * 512 + gl8];
        #pragma unroll
        for (int i = 0; i < 4; ++i)
            #pragma unroll
            for (int j = 0; j < 4; ++j)
                acc[i][j] = __builtin_amdgcn_mfma_f32_16x16x32_f16(av[i], bv[j], acc[i][j], 0, 0, 0);
        if (t + 1 < NKT_) {
            VMW0();
            __builtin_amdgcn_s_barrier();
        }
    }

    // epilogue: C/D layout col=fr, row=g*4+rr
    #pragma unroll
    for (int mi = 0; mi < 4; ++mi) {
        #pragma unroll
        for (int rr = 0; rr < 4; ++rr) {
            const int row = m0 + wm * 64 + mi * 16 + g * 4 + rr;
            if (row < M) {
                const int bi = b_idx[row / N_];
                #pragma unroll
                for (int ni = 0; ni < 4; ++ni) {
                    const int col = n0 + wn * 64 + ni * 16 + fr;
                    float v = acc[mi][ni][rr];
                    if (MODE == 0) {
                        float bias = 0.f;
                        if (col < DIM_) bias = qb[bi * DIM_ + col];
                        else if (col >= 2 * DIM_) bias = vb[bi * DIM_ + (col - 2 * DIM_)];
                        out_h[(size_t)row * Nout + col] = (_Float16)(v + bias);
                    } else {
                        out_f[(size_t)row * Nout + col] = v + pb[bi * DIM_ + col];
                    }
                }
            }
        }
    }
}

// ---------------- MFMA attention: one block per (b, h, 64-row q-tile) ----------------
__global__ __launch_bounds__(256) void attn_mfma(
    const _Float16* __restrict__ qkv, const float* __restrict__ biasT,
    _Float16* __restrict__ ctx)
{
    __shared__ __align__(16) _Float16 KP[NP_ * KSTR_];   // K tile, reused as P tile
    __shared__ __align__(16) _Float16 VT[HD_ * VSTR_];   // V^T tile

    const int b = blockIdx.z, h = blockIdx.y, rt = blockIdx.x;
    const int r0 = rt * 64;
    const int tid = threadIdx.x, lane = tid & 63, w = tid >> 6;
    const int fr = lane & 15, g = lane >> 4;

    const size_t baseQ = (size_t)b * N_ * K3_ + h * HD_;
    const size_t baseK = baseQ + DIM_;
    const size_t baseV = baseQ + 2 * DIM_;

    for (int idx = tid; idx < NP_ * 8; idx += 256) {
        int row = idx % NP_, dc = idx / NP_;
        int gk = min(row, N_ - 1);
        f16x8 v = *(const f16x8*)(qkv + baseK + (size_t)gk * K3_ + dc * 8);
        *(f16x8*)(KP + row * KSTR_ + dc * 8) = v;
    }
    for (int idx = tid; idx < 112 * 8; idx += 256) {
        int jp = idx % 112, dc = idx / 112;
        int j0 = 2 * jp, j1 = 2 * jp + 1;
        f16x8 zz = {};
        f16x8 v0 = (j0 < N_) ? *(const f16x8*)(qkv + baseV + (size_t)j0 * K3_ + dc * 8) : zz;
        f16x8 v1 = (j1 < N_) ? *(const f16x8*)(qkv + baseV + (size_t)j1 * K3_ + dc * 8) : zz;
        #pragma unroll
        for (int e = 0; e < 8; ++e) {
            f16x2 p; p[0] = v0[e]; p[1] = v1[e];
            *(f16x2*)(VT + (dc * 8 + e) * VSTR_ + 2 * jp) = p;
        }
    }
    const int qrow = min(r0 + w * 16 + fr, N_ - 1);
    f16x8 qf[2];
    qf[0] = *(const f16x8*)(qkv + baseQ + (size_t)qrow * K3_ + g * 8);
    qf[1] = *(const f16x8*)(qkv + baseQ + (size_t)qrow * K3_ + 32 + g * 8);

    __syncthreads();

    f32x4 acc[13];
    #pragma unroll
    for (int jf = 0; jf < 13; ++jf) acc[jf] = (f32x4)0.f;
    #pragma unroll
    for (int jf = 0; jf < 13; ++jf) {
        #pragma unroll
        for (int kk = 0; kk < 2; ++kk) {
            f16x8 a = *(const f16x8*)&KP[(jf * 16 + fr) * KSTR_ + kk * 32 + g * 8];
            acc[jf] = __builtin_amdgcn_mfma_f32_16x16x32_f16(a, qf[kk], acc[jf], 0, 0, 0);
        }
    }

    const int qb_ = min(r0 + w * 16 + fr, NP_ - 1);
    const float* bp = biasT + (size_t)h * NP_ * NP_ + qb_;
    float mx = -3e38f;
    #pragma unroll
    for (int jf = 0; jf < 13; ++jf) {
        #pragma unroll
        for (int r = 0; r < 4; ++r) {
            int k = jf * 16 + g * 4 + r;
            float s = acc[jf][r] * SCALE_ + bp[(size_t)k * NP_];
            acc[jf][r] = s;
            mx = fmaxf(mx, s);
        }
    }
    mx = fmaxf(mx, __shfl_xor(mx, 16));
    mx = fmaxf(mx, __shfl_xor(mx, 32));
    float sum = 0.f;
    #pragma unroll
    for (int jf = 0; jf < 13; ++jf) {
        #pragma unroll
        for (int r = 0; r < 4; ++r) {
            float e = __expf(acc[jf][r] - mx);
            acc[jf][r] = e;
            sum += e;
        }
    }
    sum += __shfl_xor(sum, 16);
    sum += __shfl_xor(sum, 32);
    const float inv = 1.f / sum;

    __syncthreads();

    #pragma unroll
    for (int jf = 0; jf < 13; ++jf) {
        f16x4 p;
        #pragma unroll
        for (int r = 0; r < 4; ++r) p[r] = (_Float16)(acc[jf][r] * inv);
        *(f16x4*)(KP + (size_t)(w * 16 + fr) * VSTR_ + jf * 16 + g * 4) = p;
    }
    {
        f16x4 z = {};
        *(f16x4*)(KP + (size_t)(w * 16 + fr) * VSTR_ + NP_ + g * 4) = z;
    }
    __syncthreads();

    f32x4 oacc[4];
    #pragma unroll
    for (int dj = 0; dj < 4; ++dj) oacc[dj] = (f32x4)0.f;
    #pragma unroll
    for (int ks = 0; ks < 7; ++ks) {
        f16x8 a = *(const f16x8*)&KP[(size_t)(w * 16 + fr) * VSTR_ + ks * 32 + g * 8];
        #pragma unroll
        for (int dj = 0; dj < 4; ++dj) {
            f16x8 bf = *(const f16x8*)&VT[(dj * 16 + fr) * VSTR_ + ks * 32 + g * 8];
            oacc[dj] = __builtin_amdgcn_mfma_f32_16x16x32_f16(a, bf, oacc[dj], 0, 0, 0);
        }
    }
    #pragma unroll
    for (int dj = 0; dj < 4; ++dj) {
        #pragma unroll
        for (int r = 0; r < 4; ++r) {
            const int q = r0 + w * 16 + g * 4 + r;
            if (q < N_)
                ctx[((size_t)b * N_ + q) * DIM_ + h * HD_ + dj * 16 + fr] =
                    (_Float16)oacc[dj][r];
        }
    }
}

// ---------------- launcher ----------------
extern "C" void kernel_launch(void* const* d_in, const int* in_sizes, int n_in,
                              void* d_out, int out_size, void* d_ws, size_t ws_size,
                              hipStream_t stream) {
    const float* x     = (const float*)d_in[0];
    const float* wqkv  = (const float*)d_in[1];
    const float* qb    = (const float*)d_in[2];
    const float* vb    = (const float*)d_in[3];
    const float* rt    = (const float*)d_in[4];
    const float* wproj = (const float*)d_in[5];
    const float* pbias = (const float*)d_in[6];
    const int* b_idx   = (const int*)d_in[7];
    const int* rel_idx = (const int*)d_in[8];
    float* out = (float*)d_out;

    char* ws = (char*)d_ws;
    size_t off = 0;
    auto alloc = [&](size_t bytes) -> void* {
        void* p = ws + off; off += (bytes + 255) & ~(size_t)255; return p;
    };
    _Float16* xb    = (_Float16*)alloc((size_t)M_ * DIM_ * 2);
    _Float16* wqh   = (_Float16*)alloc((size_t)K3_ * DIM_ * 2);
    _Float16* wph   = (_Float16*)alloc((size_t)DIM_ * DIM_ * 2);
    _Float16* qkvh  = (_Float16*)alloc((size_t)M_ * K3_ * 2);
    _Float16* ctx   = (_Float16*)alloc((size_t)M_ * DIM_ * 2);
    float*    biasT = (float*)alloc((size_t)HEADS_ * NP_ * NP_ * 4);

    cvt_f32_f16<<<dim3((M_ * DIM_ / 4 + 255) / 256), 256, 0, stream>>>(x, xb, M_ * DIM_ / 4);
    cvt_f32_f16<<<dim3((K3_ * DIM_ / 4 + 255) / 256), 256, 0, stream>>>(wqkv, wqh, K3_ * DIM_ / 4);
    cvt_f32_f16<<<dim3((DIM_ * DIM_ / 4 + 255) / 256), 256, 0, stream>>>(wproj, wph, DIM_ * DIM_ / 4);
    biasT_pre<<<dim3((HEADS_ * NP_ * NP_ + 255) / 256), 256, 0, stream>>>(rel_idx, rt, biasT);

    gemm_db<0><<<dim3(K3_ / 128, (M_ + 255) / 256), 512, 0, stream>>>(
        xb, wqh, M_, K3_, qb, vb, nullptr, b_idx, qkvh, nullptr);

    attn_mfma<<<dim3(4, HEADS_, B_), 256, 0, stream>>>(qkvh, biasT, ctx);

    gemm_db<1><<<dim3(DIM_ / 128, (M_ + 255) / 256), 512, 0, stream>>>(
        ctx, wph, M_, DIM_, nullptr, nullptr, pbias, b_idx, nullptr, out);
}

// Round 7
// 196.637 us; speedup vs baseline: 1.3064x; 1.0045x over previous
//
#include <hip/hip_runtime.h>
#include <stdint.h>

#define B_     64
#define N_     197
#define DIM_   768
#define HEADS_ 12
#define HD_    64
#define M_     (B_*N_)      // 12608
#define K3_    (3*DIM_)     // 2304
#define NP_    208          // padded N (13*16)
#define KSTR_  72           // attn K_lds row stride (f16)
#define VSTR_  232          // attn VT / P row stride (f16)
#define SCALE_ 0.125f
#define GK_    768          // GEMM K (both gemms)
#define NKT_   24           // GK_/32

typedef _Float16 f16x8 __attribute__((ext_vector_type(8)));
typedef _Float16 f16x4 __attribute__((ext_vector_type(4)));
typedef _Float16 f16x2 __attribute__((ext_vector_type(2)));
typedef float    f32x4 __attribute__((ext_vector_type(4)));

__device__ __forceinline__ void gload_lds16(const void* g, void* l) {
    __builtin_amdgcn_global_load_lds(
        (const __attribute__((address_space(1))) uint32_t*)g,
        (__attribute__((address_space(3))) uint32_t*)l, 16, 0, 0);
}

// ---------------- f32 -> f16 convert ----------------
__global__ __launch_bounds__(256) void cvt_f32_f16(const float* __restrict__ s,
                                                   _Float16* __restrict__ d, int n4) {
    int i = blockIdx.x * 256 + threadIdx.x;
    if (i < n4) {
        const float4 v = *(const float4*)(s + (size_t)i * 4);
        f16x4 o;
        o[0] = (_Float16)v.x; o[1] = (_Float16)v.y;
        o[2] = (_Float16)v.z; o[3] = (_Float16)v.w;
        *(f16x4*)(d + (size_t)i * 4) = o;
    }
}

// ---------------- transposed rel-pos bias: biasT[h][k][q], padded 208x208 ----------------
__global__ __launch_bounds__(256) void biasT_pre(const int* __restrict__ rel_index,
                                                 const float* __restrict__ rel_table,
                                                 float* __restrict__ biasT) {
    int t = blockIdx.x * 256 + threadIdx.x;
    if (t < HEADS_ * NP_ * NP_) {
        int h = t / (NP_ * NP_), rem = t - h * (NP_ * NP_);
        int k = rem / NP_, q = rem - k * NP_;
        float v;
        if (k >= N_)      v = -1e30f;   // padded key -> exp()->0
        else if (q >= N_) v = 0.f;      // padded query -> finite, never stored
        else              v = rel_table[rel_index[q * N_ + k] * HEADS_ + h];
        biasT[t] = v;
    }
}

// ---------------- 256x128 MFMA GEMM, BK=32, 3-buffer counted-vmcnt pipeline ----
// C[M x Nout] = A[M x 768] * Bw[Nout x 768]^T (+ bias per MODE)
// 512 thr = 8 waves (4 M x 2 N), each wave 64x64 output.
// LDS per buf: A 16KB + B 8KB; 3 bufs = 72KB -> 2 blocks/CU.
// Pipeline: stage(t) issued at iter t-2, waited with vmcnt(3) at iter t
// (stage t+1's 3 loads stay in flight) -> 2 compute phases of latency cover.
// Granule swizzle (zero-conflict, verified r3-r6): linear gload_lds dest,
// source lane permuted lx = lane^(lane>>3); read granule ((4fr+g)^(fr>>1)).
template <int MODE>
__global__ __launch_bounds__(512, 2) void gemm_db(
    const _Float16* __restrict__ A, const _Float16* __restrict__ Bw,
    int M, int Nout,
    const float* __restrict__ qb, const float* __restrict__ vb,
    const float* __restrict__ pb, const int* __restrict__ b_idx,
    _Float16* __restrict__ out_h, float* __restrict__ out_f)
{
    __shared__ __align__(16) _Float16 As[3][16 * 512];
    __shared__ __align__(16) _Float16 Bs[3][8 * 512];

    const int tid  = threadIdx.x;
    const int lane = tid & 63, w = tid >> 6;
    const int wm = w >> 1, wn = w & 1;              // 4 M-waves x 2 N-waves
    const int fr = lane & 15, g = lane >> 4;
    const int gl8 = ((4 * fr + g) ^ (fr >> 1)) * 8; // swizzled read offset in chunk
    const int lx = lane ^ (lane >> 3);              // staging source permutation
    const int sr = lx >> 2, sc8 = (lx & 3) * 8;

    // ---- bijective XCD-chunk swizzle (m204) ----
    const int gx = Nout / 128;                      // N-tiles (inner)
    const int gy = (M + 255) / 256;                 // M-tiles
    const int nwg = gx * gy;
    const int wgid = blockIdx.x + blockIdx.y * gx;
    const int q8 = nwg >> 3, r8 = nwg & 7;
    const int xcd = wgid & 7, lid = wgid >> 3;
    const int nid = (xcd < r8) ? xcd * (q8 + 1) + lid
                               : r8 * (q8 + 1) + (xcd - r8) * q8 + lid;
    const int m0 = (nid / gx) * 256, n0 = (nid % gx) * 128;

    f32x4 acc[4][4];
    #pragma unroll
    for (int i = 0; i < 4; ++i)
        #pragma unroll
        for (int j = 0; j < 4; ++j) acc[i][j] = (f32x4)0.f;

    // stage K-tile kt into buf: per thread 2 A-gloads + 1 B-gload (3 total)
    auto stage = [&](int buf, int kt) {
        #pragma unroll
        for (int iss = 0; iss < 2; ++iss) {
            int grow = m0 + w * 32 + iss * 16 + sr;
            if (grow >= M) grow = M - 1;
            gload_lds16(A + (size_t)grow * GK_ + kt * 32 + sc8,
                        &As[buf][(2 * w + iss) * 512]);
        }
        int brow = n0 + w * 16 + sr;                // Nout % 128 == 0
        gload_lds16(Bw + (size_t)brow * GK_ + kt * 32 + sc8,
                    &Bs[buf][w * 512]);
    };

    // prologue: two stages in flight
    stage(0, 0);
    stage(1, 1);

    for (int t = 0; t < NKT_; ++t) {
        // drain exactly stage(t); keep stage(t+1) in flight
        if (t + 1 < NKT_) { asm volatile("s_waitcnt vmcnt(3)" ::: "memory"); }
        else              { asm volatile("s_waitcnt vmcnt(0)" ::: "memory"); }
        __builtin_amdgcn_s_barrier();
        __builtin_amdgcn_sched_barrier(0);
        if (t + 2 < NKT_) stage((t + 2) % 3, t + 2);

        const _Float16* Ac = &As[t % 3][0];
        const _Float16* Bc = &Bs[t % 3][0];
        f16x8 av[4], bv[4];
        #pragma unroll
        for (int i = 0; i < 4; ++i)
            av[i] = *(const f16x8*)&Ac[(wm * 4 + i) * 512 + gl8];
        #pragma unroll
        for (int j = 0; j < 4; ++j)
            bv[j] = *(const f16x8*)&Bc[(wn * 4 + j) * 512 + gl8];
        __builtin_amdgcn_s_setprio(1);
        #pragma unroll
        for (int i = 0; i < 4; ++i)
            #pragma unroll
            for (int j = 0; j < 4; ++j)
                acc[i][j] = __builtin_amdgcn_mfma_f32_16x16x32_f16(av[i], bv[j], acc[i][j], 0, 0, 0);
        __builtin_amdgcn_s_setprio(0);
    }

    // epilogue: C/D layout col=fr, row=g*4+rr
    #pragma unroll
    for (int mi = 0; mi < 4; ++mi) {
        #pragma unroll
        for (int rr = 0; rr < 4; ++rr) {
            const int row = m0 + wm * 64 + mi * 16 + g * 4 + rr;
            if (row < M) {
                const int bi = b_idx[row / N_];
                #pragma unroll
                for (int ni = 0; ni < 4; ++ni) {
                    const int col = n0 + wn * 64 + ni * 16 + fr;
                    float v = acc[mi][ni][rr];
                    if (MODE == 0) {
                        float bias = 0.f;
                        if (col < DIM_) bias = qb[bi * DIM_ + col];
                        else if (col >= 2 * DIM_) bias = vb[bi * DIM_ + (col - 2 * DIM_)];
                        out_h[(size_t)row * Nout + col] = (_Float16)(v + bias);
                    } else {
                        out_f[(size_t)row * Nout + col] = v + pb[bi * DIM_ + col];
                    }
                }
            }
        }
    }
}

// ---------------- MFMA attention: one block per (b, h, 64-row q-tile) ----------------
__global__ __launch_bounds__(256) void attn_mfma(
    const _Float16* __restrict__ qkv, const float* __restrict__ biasT,
    _Float16* __restrict__ ctx)
{
    __shared__ __align__(16) _Float16 KP[NP_ * KSTR_];   // K tile, reused as P tile
    __shared__ __align__(16) _Float16 VT[HD_ * VSTR_];   // V^T tile

    const int b = blockIdx.z, h = blockIdx.y, rt = blockIdx.x;
    const int r0 = rt * 64;
    const int tid = threadIdx.x, lane = tid & 63, w = tid >> 6;
    const int fr = lane & 15, g = lane >> 4;

    const size_t baseQ = (size_t)b * N_ * K3_ + h * HD_;
    const size_t baseK = baseQ + DIM_;
    const size_t baseV = baseQ + 2 * DIM_;

    for (int idx = tid; idx < NP_ * 8; idx += 256) {
        int row = idx % NP_, dc = idx / NP_;
        int gk = min(row, N_ - 1);
        f16x8 v = *(const f16x8*)(qkv + baseK + (size_t)gk * K3_ + dc * 8);
        *(f16x8*)(KP + row * KSTR_ + dc * 8) = v;
    }
    for (int idx = tid; idx < 112 * 8; idx += 256) {
        int jp = idx % 112, dc = idx / 112;
        int j0 = 2 * jp, j1 = 2 * jp + 1;
        f16x8 zz = {};
        f16x8 v0 = (j0 < N_) ? *(const f16x8*)(qkv + baseV + (size_t)j0 * K3_ + dc * 8) : zz;
        f16x8 v1 = (j1 < N_) ? *(const f16x8*)(qkv + baseV + (size_t)j1 * K3_ + dc * 8) : zz;
        #pragma unroll
        for (int e = 0; e < 8; ++e) {
            f16x2 p; p[0] = v0[e]; p[1] = v1[e];
            *(f16x2*)(VT + (dc * 8 + e) * VSTR_ + 2 * jp) = p;
        }
    }
    const int qrow = min(r0 + w * 16 + fr, N_ - 1);
    f16x8 qf[2];
    qf[0] = *(const f16x8*)(qkv + baseQ + (size_t)qrow * K3_ + g * 8);
    qf[1] = *(const f16x8*)(qkv + baseQ + (size_t)qrow * K3_ + 32 + g * 8);

    __syncthreads();

    f32x4 acc[13];
    #pragma unroll
    for (int jf = 0; jf < 13; ++jf) acc[jf] = (f32x4)0.f;
    #pragma unroll
    for (int jf = 0; jf < 13; ++jf) {
        #pragma unroll
        for (int kk = 0; kk < 2; ++kk) {
            f16x8 a = *(const f16x8*)&KP[(jf * 16 + fr) * KSTR_ + kk * 32 + g * 8];
            acc[jf] = __builtin_amdgcn_mfma_f32_16x16x32_f16(a, qf[kk], acc[jf], 0, 0, 0);
        }
    }

    const int qb_ = min(r0 + w * 16 + fr, NP_ - 1);
    const float* bp = biasT + (size_t)h * NP_ * NP_ + qb_;
    float mx = -3e38f;
    #pragma unroll
    for (int jf = 0; jf < 13; ++jf) {
        #pragma unroll
        for (int r = 0; r < 4; ++r) {
            int k = jf * 16 + g * 4 + r;
            float s = acc[jf][r] * SCALE_ + bp[(size_t)k * NP_];
            acc[jf][r] = s;
            mx = fmaxf(mx, s);
        }
    }
    mx = fmaxf(mx, __shfl_xor(mx, 16));
    mx = fmaxf(mx, __shfl_xor(mx, 32));
    float sum = 0.f;
    #pragma unroll
    for (int jf = 0; jf < 13; ++jf) {
        #pragma unroll
        for (int r = 0; r < 4; ++r) {
            float e = __expf(acc[jf][r] - mx);
            acc[jf][r] = e;
            sum += e;
        }
    }
    sum += __shfl_xor(sum, 16);
    sum += __shfl_xor(sum, 32);
    const float inv = 1.f / sum;

    __syncthreads();

    #pragma unroll
    for (int jf = 0; jf < 13; ++jf) {
        f16x4 p;
        #pragma unroll
        for (int r = 0; r < 4; ++r) p[r] = (_Float16)(acc[jf][r] * inv);
        *(f16x4*)(KP + (size_t)(w * 16 + fr) * VSTR_ + jf * 16 + g * 4) = p;
    }
    {
        f16x4 z = {};
        *(f16x4*)(KP + (size_t)(w * 16 + fr) * VSTR_ + NP_ + g * 4) = z;
    }
    __syncthreads();

    f32x4 oacc[4];
    #pragma unroll
    for (int dj = 0; dj < 4; ++dj) oacc[dj] = (f32x4)0.f;
    #pragma unroll
    for (int ks = 0; ks < 7; ++ks) {
        f16x8 a = *(const f16x8*)&KP[(size_t)(w * 16 + fr) * VSTR_ + ks * 32 + g * 8];
        #pragma unroll
        for (int dj = 0; dj < 4; ++dj) {
            f16x8 bf = *(const f16x8*)&VT[(dj * 16 + fr) * VSTR_ + ks * 32 + g * 8];
            oacc[dj] = __builtin_amdgcn_mfma_f32_16x16x32_f16(a, bf, oacc[dj], 0, 0, 0);
        }
    }
    #pragma unroll
    for (int dj = 0; dj < 4; ++dj) {
        #pragma unroll
        for (int r = 0; r < 4; ++r) {
            const int q = r0 + w * 16 + g * 4 + r;
            if (q < N_)
                ctx[((size_t)b * N_ + q) * DIM_ + h * HD_ + dj * 16 + fr] =
                    (_Float16)oacc[dj][r];
        }
    }
}

// ---------------- launcher ----------------
extern "C" void kernel_launch(void* const* d_in, const int* in_sizes, int n_in,
                              void* d_out, int out_size, void* d_ws, size_t ws_size,
                              hipStream_t stream) {
    const float* x     = (const float*)d_in[0];
    const float* wqkv  = (const float*)d_in[1];
    const float* qb    = (const float*)d_in[2];
    const float* vb    = (const float*)d_in[3];
    const float* rt    = (const float*)d_in[4];
    const float* wproj = (const float*)d_in[5];
    const float* pbias = (const float*)d_in[6];
    const int* b_idx   = (const int*)d_in[7];
    const int* rel_idx = (const int*)d_in[8];
    float* out = (float*)d_out;

    char* ws = (char*)d_ws;
    size_t off = 0;
    auto alloc = [&](size_t bytes) -> void* {
        void* p = ws + off; off += (bytes + 255) & ~(size_t)255; return p;
    };
    _Float16* xb    = (_Float16*)alloc((size_t)M_ * DIM_ * 2);
    _Float16* wqh   = (_Float16*)alloc((size_t)K3_ * DIM_ * 2);
    _Float16* wph   = (_Float16*)alloc((size_t)DIM_ * DIM_ * 2);
    _Float16* qkvh  = (_Float16*)alloc((size_t)M_ * K3_ * 2);
    _Float16* ctx   = (_Float16*)alloc((size_t)M_ * DIM_ * 2);
    float*    biasT = (float*)alloc((size_t)HEADS_ * NP_ * NP_ * 4);

    cvt_f32_f16<<<dim3((M_ * DIM_ / 4 + 255) / 256), 256, 0, stream>>>(x, xb, M_ * DIM_ / 4);
    cvt_f32_f16<<<dim3((K3_ * DIM_ / 4 + 255) / 256), 256, 0, stream>>>(wqkv, wqh, K3_ * DIM_ / 4);
    cvt_f32_f16<<<dim3((DIM_ * DIM_ / 4 + 255) / 256), 256, 0, stream>>>(wproj, wph, DIM_ * DIM_ / 4);
    biasT_pre<<<dim3((HEADS_ * NP_ * NP_ + 255) / 256), 256, 0, stream>>>(rel_idx, rt, biasT);

    gemm_db<0><<<dim3(K3_ / 128, (M_ + 255) / 256), 512, 0, stream>>>(
        xb, wqh, M_, K3_, qb, vb, nullptr, b_idx, qkvh, nullptr);

    attn_mfma<<<dim3(4, HEADS_, B_), 256, 0, stream>>>(qkvh, biasT, ctx);

    gemm_db<1><<<dim3(DIM_ / 128, (M_ + 255) / 256), 512, 0, stream>>>(
        ctx, wph, M_, DIM_, nullptr, nullptr, pbias, b_idx, nullptr, out);
}

// Round 8
// 169.726 us; speedup vs baseline: 1.5135x; 1.1586x over previous
//
#include <hip/hip_runtime.h>
#include <stdint.h>

#define B_     64
#define N_     197
#define DIM_   768
#define HEADS_ 12
#define HD_    64
#define M_     (B_*N_)      // 12608
#define K3_    (3*DIM_)     // 2304
#define NP_    208          // padded N (13*16)
#define VSTR_  232          // attn VT row stride (f16)
#define SCALE_ 0.125f
#define GK_    768          // GEMM K (both gemms)
#define NKT_   24           // GK_/32

typedef _Float16 f16x8 __attribute__((ext_vector_type(8)));
typedef _Float16 f16x4 __attribute__((ext_vector_type(4)));
typedef _Float16 f16x2 __attribute__((ext_vector_type(2)));
typedef float    f32x4 __attribute__((ext_vector_type(4)));

__device__ __forceinline__ void gload_lds16(const void* g, void* l) {
    __builtin_amdgcn_global_load_lds(
        (const __attribute__((address_space(1))) uint32_t*)g,
        (__attribute__((address_space(3))) uint32_t*)l, 16, 0, 0);
}

// ---------------- f32 -> f16 convert ----------------
__global__ __launch_bounds__(256) void cvt_f32_f16(const float* __restrict__ s,
                                                   _Float16* __restrict__ d, int n4) {
    int i = blockIdx.x * 256 + threadIdx.x;
    if (i < n4) {
        const float4 v = *(const float4*)(s + (size_t)i * 4);
        f16x4 o;
        o[0] = (_Float16)v.x; o[1] = (_Float16)v.y;
        o[2] = (_Float16)v.z; o[3] = (_Float16)v.w;
        *(f16x4*)(d + (size_t)i * 4) = o;
    }
}

// ---------------- transposed rel-pos bias: biasT[h][k][q], padded 208x208 ----------------
__global__ __launch_bounds__(256) void biasT_pre(const int* __restrict__ rel_index,
                                                 const float* __restrict__ rel_table,
                                                 float* __restrict__ biasT) {
    int t = blockIdx.x * 256 + threadIdx.x;
    if (t < HEADS_ * NP_ * NP_) {
        int h = t / (NP_ * NP_), rem = t - h * (NP_ * NP_);
        int k = rem / NP_, q = rem - k * NP_;
        float v;
        if (k >= N_)      v = -1e30f;   // padded key -> exp()->0
        else if (q >= N_) v = 0.f;      // padded query -> finite, never stored
        else              v = rel_table[rel_index[q * N_ + k] * HEADS_ + h];
        biasT[t] = v;
    }
}

// ---------------- 256x128 MFMA GEMM, BK=32, 3-buffer counted-vmcnt pipeline ----
// (unchanged from r7 — isolating the attn rewrite this round)
template <int MODE>
__global__ __launch_bounds__(512, 2) void gemm_db(
    const _Float16* __restrict__ A, const _Float16* __restrict__ Bw,
    int M, int Nout,
    const float* __restrict__ qb, const float* __restrict__ vb,
    const float* __restrict__ pb, const int* __restrict__ b_idx,
    _Float16* __restrict__ out_h, float* __restrict__ out_f)
{
    __shared__ __align__(16) _Float16 As[3][16 * 512];
    __shared__ __align__(16) _Float16 Bs[3][8 * 512];

    const int tid  = threadIdx.x;
    const int lane = tid & 63, w = tid >> 6;
    const int wm = w >> 1, wn = w & 1;              // 4 M-waves x 2 N-waves
    const int fr = lane & 15, g = lane >> 4;
    const int gl8 = ((4 * fr + g) ^ (fr >> 1)) * 8; // swizzled read offset in chunk
    const int lx = lane ^ (lane >> 3);              // staging source permutation
    const int sr = lx >> 2, sc8 = (lx & 3) * 8;

    // bijective XCD-chunk swizzle (m204)
    const int gx = Nout / 128;
    const int gy = (M + 255) / 256;
    const int nwg = gx * gy;
    const int wgid = blockIdx.x + blockIdx.y * gx;
    const int q8 = nwg >> 3, r8 = nwg & 7;
    const int xcd = wgid & 7, lid = wgid >> 3;
    const int nid = (xcd < r8) ? xcd * (q8 + 1) + lid
                               : r8 * (q8 + 1) + (xcd - r8) * q8 + lid;
    const int m0 = (nid / gx) * 256, n0 = (nid % gx) * 128;

    f32x4 acc[4][4];
    #pragma unroll
    for (int i = 0; i < 4; ++i)
        #pragma unroll
        for (int j = 0; j < 4; ++j) acc[i][j] = (f32x4)0.f;

    auto stage = [&](int buf, int kt) {
        #pragma unroll
        for (int iss = 0; iss < 2; ++iss) {
            int grow = m0 + w * 32 + iss * 16 + sr;
            if (grow >= M) grow = M - 1;
            gload_lds16(A + (size_t)grow * GK_ + kt * 32 + sc8,
                        &As[buf][(2 * w + iss) * 512]);
        }
        int brow = n0 + w * 16 + sr;
        gload_lds16(Bw + (size_t)brow * GK_ + kt * 32 + sc8,
                    &Bs[buf][w * 512]);
    };

    stage(0, 0);
    stage(1, 1);

    for (int t = 0; t < NKT_; ++t) {
        if (t + 1 < NKT_) { asm volatile("s_waitcnt vmcnt(3)" ::: "memory"); }
        else              { asm volatile("s_waitcnt vmcnt(0)" ::: "memory"); }
        __builtin_amdgcn_s_barrier();
        __builtin_amdgcn_sched_barrier(0);
        if (t + 2 < NKT_) stage((t + 2) % 3, t + 2);

        const _Float16* Ac = &As[t % 3][0];
        const _Float16* Bc = &Bs[t % 3][0];
        f16x8 av[4], bv[4];
        #pragma unroll
        for (int i = 0; i < 4; ++i)
            av[i] = *(const f16x8*)&Ac[(wm * 4 + i) * 512 + gl8];
        #pragma unroll
        for (int j = 0; j < 4; ++j)
            bv[j] = *(const f16x8*)&Bc[(wn * 4 + j) * 512 + gl8];
        __builtin_amdgcn_s_setprio(1);
        #pragma unroll
        for (int i = 0; i < 4; ++i)
            #pragma unroll
            for (int j = 0; j < 4; ++j)
                acc[i][j] = __builtin_amdgcn_mfma_f32_16x16x32_f16(av[i], bv[j], acc[i][j], 0, 0, 0);
        __builtin_amdgcn_s_setprio(0);
    }

    #pragma unroll
    for (int mi = 0; mi < 4; ++mi) {
        #pragma unroll
        for (int rr = 0; rr < 4; ++rr) {
            const int row = m0 + wm * 64 + mi * 16 + g * 4 + rr;
            if (row < M) {
                const int bi = b_idx[row / N_];
                #pragma unroll
                for (int ni = 0; ni < 4; ++ni) {
                    const int col = n0 + wn * 64 + ni * 16 + fr;
                    float v = acc[mi][ni][rr];
                    if (MODE == 0) {
                        float bias = 0.f;
                        if (col < DIM_) bias = qb[bi * DIM_ + col];
                        else if (col >= 2 * DIM_) bias = vb[bi * DIM_ + (col - 2 * DIM_)];
                        out_h[(size_t)row * Nout + col] = (_Float16)(v + bias);
                    } else {
                        out_f[(size_t)row * Nout + col] = v + pb[bi * DIM_ + col];
                    }
                }
            }
        }
    }
}

// ---------------- MFMA attention v2: 128 q-rows/block, 8 waves, reg-P ----------------
// S^T = K.Q^T (swapped) -> lane-local softmax -> P repacked to PV A-fragments via
// g-dimension shuffles (no LDS round-trip, no post-staging barriers).
__global__ __launch_bounds__(512, 4) void attn_mfma(
    const _Float16* __restrict__ qkv, const float* __restrict__ biasT,
    _Float16* __restrict__ ctx)
{
    __shared__ __align__(16) _Float16 Klds[26 * 512];    // 13 jf x 2 kk chunks [16k][32d], swizzled
    __shared__ __align__(16) _Float16 VT[HD_ * VSTR_];   // V^T [64 d][224 k], stride 232

    const int b = blockIdx.z, h = blockIdx.y, rt = blockIdx.x;
    const int r0 = rt * 128;
    const int tid = threadIdx.x, lane = tid & 63, w = tid >> 6;
    const int fr = lane & 15, g = lane >> 4;
    const int gl8 = ((4 * fr + g) ^ (fr >> 1)) * 8;

    const size_t baseQ = (size_t)b * N_ * K3_ + h * HD_;
    const size_t baseK = baseQ + DIM_;
    const size_t baseV = baseQ + 2 * DIM_;

    // ---- K staging: 26 gload_lds chunks, pre-swizzled per-lane source ----
    {
        const int l = lane ^ (lane >> 3);            // involution
        const int cr = l >> 2, cc = (l & 3) * 8;
        for (int c = w; c < 26; c += 8) {
            const int jf = c >> 1, kk = c & 1;
            int grow = jf * 16 + cr; if (grow > N_ - 1) grow = N_ - 1;
            gload_lds16(qkv + baseK + (size_t)grow * K3_ + kk * 32 + cc,
                        &Klds[c * 512]);
        }
    }
    // ---- V^T staging [64 d][224 k], zero-fill k >= N_ ----
    for (int idx = tid; idx < 112 * 8; idx += 512) {
        int jp = idx % 112, dc = idx / 112;
        int j0 = 2 * jp, j1 = 2 * jp + 1;
        f16x8 zz = {};
        f16x8 v0 = (j0 < N_) ? *(const f16x8*)(qkv + baseV + (size_t)j0 * K3_ + dc * 8) : zz;
        f16x8 v1 = (j1 < N_) ? *(const f16x8*)(qkv + baseV + (size_t)j1 * K3_ + dc * 8) : zz;
        #pragma unroll
        for (int e = 0; e < 8; ++e) {
            f16x2 p; p[0] = v0[e]; p[1] = v1[e];
            *(f16x2*)(VT + (dc * 8 + e) * VSTR_ + 2 * jp) = p;
        }
    }
    // ---- Q fragments: wave w owns q rows r0+w*16..+15 ----
    int qrow = r0 + w * 16 + fr; if (qrow > N_ - 1) qrow = N_ - 1;
    f16x8 qf[2];
    qf[0] = *(const f16x8*)(qkv + baseQ + (size_t)qrow * K3_ + g * 8);
    qf[1] = *(const f16x8*)(qkv + baseQ + (size_t)qrow * K3_ + 32 + g * 8);

    __syncthreads();   // the only barrier

    // ---- S^T[k][q]: lane (g,fr) -> k = 16jf+4g+r, q = r0+w*16+fr ----
    f32x4 p[13];
    #pragma unroll
    for (int jf = 0; jf < 13; ++jf) p[jf] = (f32x4)0.f;
    #pragma unroll
    for (int jf = 0; jf < 13; ++jf) {
        #pragma unroll
        for (int kk = 0; kk < 2; ++kk) {
            f16x8 a = *(const f16x8*)&Klds[(jf * 2 + kk) * 512 + gl8];
            p[jf] = __builtin_amdgcn_mfma_f32_16x16x32_f16(a, qf[kk], p[jf], 0, 0, 0);
        }
    }

    // ---- softmax (lane-local + 2 shfl) ----
    const int qb_ = min(r0 + w * 16 + fr, NP_ - 1);
    const float* bp = biasT + (size_t)h * NP_ * NP_ + qb_;
    float mx = -3e38f;
    #pragma unroll
    for (int jf = 0; jf < 13; ++jf) {
        #pragma unroll
        for (int r = 0; r < 4; ++r) {
            int k = jf * 16 + g * 4 + r;
            float s = p[jf][r] * SCALE_ + bp[(size_t)k * NP_];
            p[jf][r] = s;
            mx = fmaxf(mx, s);
        }
    }
    mx = fmaxf(mx, __shfl_xor(mx, 16));
    mx = fmaxf(mx, __shfl_xor(mx, 32));
    float sum = 0.f;
    #pragma unroll
    for (int jf = 0; jf < 13; ++jf) {
        #pragma unroll
        for (int r = 0; r < 4; ++r) {
            float e = __expf(p[jf][r] - mx);
            p[jf][r] = e;
            sum += e;
        }
    }
    sum += __shfl_xor(sum, 16);
    sum += __shfl_xor(sum, 32);
    const float inv = 1.f / sum;

    // ---- PV: A-frag[e] of lane(g,fr) = P[fr][32ks+8g+e], via g-permutation shuffles ----
    const int src0 = ((2 * g) & 3) * 16 + fr;
    const int src1 = ((2 * g + 1) & 3) * 16 + fr;
    const bool hi = (g >= 2);
    f32x4 oacc[4];
    #pragma unroll
    for (int dj = 0; dj < 4; ++dj) oacc[dj] = (f32x4)0.f;

    #pragma unroll
    for (int ks = 0; ks < 7; ++ks) {
        // own packed pairs: a = jf 2ks, b = jf 2ks+1 (absent for ks==6 -> zero)
        f16x2 t;
        t[0] = (_Float16)(p[2 * ks][0] * inv); t[1] = (_Float16)(p[2 * ks][1] * inv);
        uint32_t a01 = __builtin_bit_cast(uint32_t, t);
        t[0] = (_Float16)(p[2 * ks][2] * inv); t[1] = (_Float16)(p[2 * ks][3] * inv);
        uint32_t a23 = __builtin_bit_cast(uint32_t, t);
        uint32_t b01 = 0, b23 = 0;
        if (ks < 6) {
            t[0] = (_Float16)(p[2 * ks + 1][0] * inv); t[1] = (_Float16)(p[2 * ks + 1][1] * inv);
            b01 = __builtin_bit_cast(uint32_t, t);
            t[0] = (_Float16)(p[2 * ks + 1][2] * inv); t[1] = (_Float16)(p[2 * ks + 1][3] * inv);
            b23 = __builtin_bit_cast(uint32_t, t);
        }
        uint32_t xa, xb;
        uint32_t wd[4];
        xa = (uint32_t)__shfl((int)a01, src0); xb = (uint32_t)__shfl((int)b01, src0);
        wd[0] = hi ? xb : xa;
        xa = (uint32_t)__shfl((int)a23, src0); xb = (uint32_t)__shfl((int)b23, src0);
        wd[1] = hi ? xb : xa;
        xa = (uint32_t)__shfl((int)a01, src1); xb = (uint32_t)__shfl((int)b01, src1);
        wd[2] = hi ? xb : xa;
        xa = (uint32_t)__shfl((int)a23, src1); xb = (uint32_t)__shfl((int)b23, src1);
        wd[3] = hi ? xb : xa;
        typedef uint32_t u32x4 __attribute__((ext_vector_type(4)));
        u32x4 wv; wv[0] = wd[0]; wv[1] = wd[1]; wv[2] = wd[2]; wv[3] = wd[3];
        f16x8 af = __builtin_bit_cast(f16x8, wv);

        #pragma unroll
        for (int dj = 0; dj < 4; ++dj) {
            f16x8 bf = *(const f16x8*)&VT[(dj * 16 + fr) * VSTR_ + ks * 32 + g * 8];
            oacc[dj] = __builtin_amdgcn_mfma_f32_16x16x32_f16(af, bf, oacc[dj], 0, 0, 0);
        }
    }

    #pragma unroll
    for (int dj = 0; dj < 4; ++dj) {
        #pragma unroll
        for (int r = 0; r < 4; ++r) {
            const int q = r0 + w * 16 + g * 4 + r;
            if (q < N_)
                ctx[((size_t)b * N_ + q) * DIM_ + h * HD_ + dj * 16 + fr] =
                    (_Float16)oacc[dj][r];
        }
    }
}

// ---------------- launcher ----------------
extern "C" void kernel_launch(void* const* d_in, const int* in_sizes, int n_in,
                              void* d_out, int out_size, void* d_ws, size_t ws_size,
                              hipStream_t stream) {
    const float* x     = (const float*)d_in[0];
    const float* wqkv  = (const float*)d_in[1];
    const float* qb    = (const float*)d_in[2];
    const float* vb    = (const float*)d_in[3];
    const float* rt    = (const float*)d_in[4];
    const float* wproj = (const float*)d_in[5];
    const float* pbias = (const float*)d_in[6];
    const int* b_idx   = (const int*)d_in[7];
    const int* rel_idx = (const int*)d_in[8];
    float* out = (float*)d_out;

    char* ws = (char*)d_ws;
    size_t off = 0;
    auto alloc = [&](size_t bytes) -> void* {
        void* p = ws + off; off += (bytes + 255) & ~(size_t)255; return p;
    };
    _Float16* xb    = (_Float16*)alloc((size_t)M_ * DIM_ * 2);
    _Float16* wqh   = (_Float16*)alloc((size_t)K3_ * DIM_ * 2);
    _Float16* wph   = (_Float16*)alloc((size_t)DIM_ * DIM_ * 2);
    _Float16* qkvh  = (_Float16*)alloc((size_t)M_ * K3_ * 2);
    _Float16* ctx   = (_Float16*)alloc((size_t)M_ * DIM_ * 2);
    float*    biasT = (float*)alloc((size_t)HEADS_ * NP_ * NP_ * 4);

    cvt_f32_f16<<<dim3((M_ * DIM_ / 4 + 255) / 256), 256, 0, stream>>>(x, xb, M_ * DIM_ / 4);
    cvt_f32_f16<<<dim3((K3_ * DIM_ / 4 + 255) / 256), 256, 0, stream>>>(wqkv, wqh, K3_ * DIM_ / 4);
    cvt_f32_f16<<<dim3((DIM_ * DIM_ / 4 + 255) / 256), 256, 0, stream>>>(wproj, wph, DIM_ * DIM_ / 4);
    biasT_pre<<<dim3((HEADS_ * NP_ * NP_ + 255) / 256), 256, 0, stream>>>(rel_idx, rt, biasT);

    gemm_db<0><<<dim3(K3_ / 128, (M_ + 255) / 256), 512, 0, stream>>>(
        xb, wqh, M_, K3_, qb, vb, nullptr, b_idx, qkvh, nullptr);

    attn_mfma<<<dim3(2, HEADS_, B_), 512, 0, stream>>>(qkvh, biasT, ctx);

    gemm_db<1><<<dim3(DIM_ / 128, (M_ + 255) / 256), 512, 0, stream>>>(
        ctx, wph, M_, DIM_, nullptr, nullptr, pbias, b_idx, nullptr, out);
}